// Round 11
// baseline (14.242 us; speedup 1.0000x reference)
//
#include <hip/hip_runtime.h>
#include <hip/hip_bf16.h>
#include <hip/hip_fp16.h>

#define G_COUNT 2048
#define IMG_W 128
#define T_THR 1e-4f
#define ALPHA_MAX 0.99f
#define LOG2E 1.4426950408889634f
#define INV255 0.003921568627451f

__device__ __forceinline__ float fexp2(float x) {
#if __has_builtin(__builtin_amdgcn_exp2f)
    return __builtin_amdgcn_exp2f(x);
#else
    return __expf(x * 0.6931471805599453f);
#endif
}

__device__ __forceinline__ float frcp(float x) {
#if __has_builtin(__builtin_amdgcn_rcpf)
    return __builtin_amdgcn_rcpf(x);
#else
    return 1.0f / x;
#endif
}

__device__ __forceinline__ float clampf(float x, float lo, float hi) {
    return fminf(fmaxf(x, lo), hi);
}

// Single fused kernel: 256 blocks x 512 threads (8 waves), one 8x8 tile/block.
// Records packed to 32 B: {mx,my,A,C | B,l2o,pk(r,g),pk(b,-)}.
// alpha = exp2(l2o - s2)/255 (== o*exp(-sigma) to ~1e-6; alpha<1/255 <=> s2>l2o).
// Sort: u32 depth-bit rank sort (4 keys/b128, 2 threads/item, shfl combine),
//       exact ties resolved by original index -> matches stable argsort.
// Composite: group-interleaved with A/B register double-buffer; group g+1's
//       LDS reads issue before the s_T barrier (perm/records immutable), so
//       their latency hides under barrier + prefix + accumulate.
__global__ __launch_bounds__(512)
void raster_fused(const float* __restrict__ means2d,
                  const float* __restrict__ conics,
                  const float* __restrict__ colors,
                  const float* __restrict__ opac,
                  const float* __restrict__ depths,
                  float* __restrict__ out) {
    __shared__ alignas(16) float4 s_rec[2 * (G_COUNT + 1)];      // 64 KB
    __shared__ alignas(16) unsigned s_key[G_COUNT + 4];          // 8 KB
    __shared__ alignas(16) unsigned s_idx[G_COUNT];              // 8 KB
    __shared__ alignas(16) int s_perm[G_COUNT];                  // 8 KB
    __shared__ float s_T[2][8][64];                              // 4 KB
    __shared__ float s_rgb[8][192];                              // 6 KB
    __shared__ int s_cnt;

    const int tid = threadIdx.x;
    const int wv = tid >> 6;                         // 0..7
    const int lane = tid & 63;
    const int tile = blockIdx.x;                     // 16x16 tiles of 8x8 px
    const int tx = tile & 15;
    const int ty = tile >> 4;

    if (tid == 0) s_cnt = 0;
    __syncthreads();

    const float bx0 = (float)(tx * 8) + 0.5f;
    const float bx1 = (float)(tx * 8 + 7) + 0.5f;
    const float by0 = (float)(ty * 8) + 0.5f;
    const float by1 = (float)(ty * 8 + 7) + 0.5f;

    // ---- Phase 1: exact conic-box cull + compact packed records ----
    for (int k = 0; k < G_COUNT; k += 512) {
        int gi = k + tid;
        float2 m = ((const float2*)means2d)[gi];
        float a = conics[3 * gi + 0];
        float b = conics[3 * gi + 1];
        float c = conics[3 * gi + 2];
        float o = opac[gi];
        float d = depths[gi];

        float A = 0.5f * a * LOG2E;                  // s2 = A dx^2 + C dy^2 + B dx dy
        float C = 0.5f * c * LOG2E;                  //    = sigma * log2(e)
        float B = b * LOG2E;
        float l2o = __log2f(255.0f * o);             // o >= 0.05 -> positive

        // min of s2 over the tile rect: interior (mean inside) else boundary;
        // each edge is a 1-D quadratic, clamp its vertex to the edge range.
        float lx = bx0 - m.x, hx = bx1 - m.x;
        float ly = by0 - m.y, hy = by1 - m.y;
        bool inside = (lx <= 0.0f) & (hx >= 0.0f) & (ly <= 0.0f) & (hy >= 0.0f);
        float rC = frcp(C), rA = frcp(A);
        float d1 = clampf(-0.5f * B * lx * rC, ly, hy);
        float d2 = clampf(-0.5f * B * hx * rC, ly, hy);
        float d3 = clampf(-0.5f * B * ly * rA, lx, hx);
        float d4 = clampf(-0.5f * B * hy * rA, lx, hx);
        float m1 = fmaf(A * lx, lx, fmaf(C * d1, d1, (B * lx) * d1));
        float m2 = fmaf(A * hx, hx, fmaf(C * d2, d2, (B * hx) * d2));
        float m3 = fmaf(A * d3, d3, fmaf(C * ly, ly, (B * d3) * ly));
        float m4 = fmaf(A * d4, d4, fmaf(C * hy, hy, (B * d4) * hy));
        float minv = fminf(fminf(m1, m2), fminf(m3, m4));
        bool pass = inside || (minv <= l2o + 0.01f);    // conservative margin

        unsigned long long msk = __ballot(pass);
        int prefix = __builtin_amdgcn_mbcnt_hi((unsigned)(msk >> 32),
                     __builtin_amdgcn_mbcnt_lo((unsigned)msk, 0));
        int wbase = 0;
        if (lane == 0) wbase = atomicAdd(&s_cnt, __popcll(msk));
        wbase = __shfl(wbase, 0);
        if (pass) {
            int pos = wbase + prefix;
            __half2 rg = __floats2half2_rn(colors[3 * gi + 0], colors[3 * gi + 1]);
            __half2 bz = __floats2half2_rn(colors[3 * gi + 2], 0.0f);
            s_rec[2 * pos + 0] = make_float4(m.x, m.y, A, C);
            s_rec[2 * pos + 1] = make_float4(B, l2o,
                                             __uint_as_float(*(unsigned*)&rg),
                                             __uint_as_float(*(unsigned*)&bz));
            s_key[pos] = __float_as_uint(d);         // depths > 0: bits keep order
            s_idx[pos] = (unsigned)gi;               // stable tiebreak
        }
    }
    __syncthreads();

    // ---- Phase 2: rank sort -> s_perm[rank] = compact slot ----
    const int n = s_cnt;
    const int npad = (n + 63) & ~63;                 // groups of 64
    if (tid < 4) s_key[n + tid] = 0xFFFFFFFFu;       // quad-read pad (> any depth)
    __syncthreads();
    {
        const int nq = (n + 3) >> 2;                 // quads to scan
        const int half = tid & 1;
        const int qlo = half ? (nq >> 1) : 0;
        const int qhi = half ? nq : (nq >> 1);
        const uint4* kq = (const uint4*)s_key;
        for (int s0 = tid >> 1; s0 < n; s0 += 256) {
            unsigned key = s_key[s0];
            int rk = 0, eq = 0;
#pragma unroll 4
            for (int q = qlo; q < qhi; ++q) {        // b128: 4 keys per read
                uint4 k4 = kq[q];
                rk += (k4.x < key) ? 1 : 0;
                rk += (k4.y < key) ? 1 : 0;
                rk += (k4.z < key) ? 1 : 0;
                rk += (k4.w < key) ? 1 : 0;
                eq += (k4.x == key) ? 1 : 0;
                eq += (k4.y == key) ? 1 : 0;
                eq += (k4.z == key) ? 1 : 0;
                eq += (k4.w == key) ? 1 : 0;
            }
            rk += __shfl_xor(rk, 1);                 // partner lane^1 shares s0
            eq += __shfl_xor(eq, 1);
            if (half == 0) {
                if (eq > 1) {                        // exact depth-bit tie (rare)
                    unsigned mygi = s_idx[s0];
                    for (int j = 0; j < n; ++j)
                        rk += (s_key[j] == key && s_idx[j] < mygi) ? 1 : 0;
                }
                s_perm[rk] = s0;                     // unique ranks -> permutation
            }
        }
    }
    for (int i = n + tid; i < npad; i += 512) s_perm[i] = n;
    if (tid == 0 && n < G_COUNT) {                   // dummy record: alpha == 0
        s_rec[2 * n + 0] = make_float4(0.f, 0.f, 0.f, 0.f);
        s_rec[2 * n + 1] = make_float4(0.f, -1.f, 0.f, 0.f);  // l2o=-1 -> al=0
    }
    __syncthreads();

    // ---- Phase 3: pipelined group-interleaved composite; lane = pixel ----
    const int pxi = tx * 8 + (lane & 7);
    const int pyi = ty * 8 + (lane >> 3);
    const float px = (float)pxi + 0.5f;
    const float py = (float)pyi + 0.5f;

    float T = 1.0f;
    float accr = 0.0f, accg = 0.0f, accb = 0.0f;
    const int ngroups = npad >> 6;

#define LOAD_GRP(P, RA, RB, gbase)                                          \
    {                                                                       \
        const int4* _pp4 = (const int4*)(s_perm + (gbase));                 \
        int4 _pa = _pp4[0], _pb = _pp4[1];                                  \
        P[0] = _pa.x; P[1] = _pa.y; P[2] = _pa.z; P[3] = _pa.w;             \
        P[4] = _pb.x; P[5] = _pb.y; P[6] = _pb.z; P[7] = _pb.w;             \
        _Pragma("unroll")                                                   \
        for (int _j = 0; _j < 8; ++_j) {                                    \
            RA[_j] = s_rec[2 * P[_j] + 0];                                  \
            RB[_j] = s_rec[2 * P[_j] + 1];                                  \
        }                                                                   \
    }

#define PROC_GRP(RA, RB, NP, NRA, NRB, g)                                   \
    {                                                                       \
        float al[8], cum[8];                                                \
        float run = 1.0f;                                                   \
        _Pragma("unroll")                                                   \
        for (int j = 0; j < 8; ++j) {                                       \
            float dx = px - RA[j].x;                                        \
            float dy = py - RA[j].y;                                        \
            float s2 = fmaf(RA[j].z * dx, dx,                               \
                            fmaf(RA[j].w * dy, dy, (RB[j].x * dx) * dy));   \
            float a = fminf(fexp2(RB[j].y - s2) * INV255, ALPHA_MAX);       \
            a = (s2 < 0.0f || s2 > RB[j].y) ? 0.0f : a;                     \
            al[j] = a;                                                      \
            run *= 1.0f - a;                                                \
            cum[j] = run;                                                   \
        }                                                                   \
        s_T[(g) & 1][wv][lane] = run;                                       \
        int _gn = ((g) + 1 < ngroups) ? (g) + 1 : (g);                      \
        LOAD_GRP(NP, NRA, NRB, _gn * 64 + wv * 8)   /* prefetch */          \
        __syncthreads();                                                    \
        float pre = 1.0f, full = 1.0f;                                      \
        _Pragma("unroll")                                                   \
        for (int t = 0; t < 8; ++t) {                                       \
            float v = s_T[(g) & 1][t][lane];                                \
            full *= v;                     /* same order -> bit-uniform */  \
            if (t < wv) pre *= v;                                           \
        }                                                                   \
        float Tw0 = T * pre;               /* exact global prefix */        \
        _Pragma("unroll")                                                   \
        for (int j = 0; j < 8; ++j) {                                       \
            float Tb = Tw0 * ((j == 0) ? 1.0f : cum[j - 1]);                \
            float Tn = Tw0 * cum[j];                                        \
            float w = (Tn >= T_THR) ? al[j] * Tb : 0.0f;                    \
            unsigned urg = __float_as_uint(RB[j].z);                        \
            unsigned ub = __float_as_uint(RB[j].w);                         \
            float2 rg = __half22float2(*(__half2*)&urg);                    \
            float2 b2 = __half22float2(*(__half2*)&ub);                     \
            accr = fmaf(w, rg.x, accr);                                     \
            accg = fmaf(w, rg.y, accg);                                     \
            accb = fmaf(w, b2.x, accb);                                     \
        }                                                                   \
        T *= full;                         /* bit-uniform across waves */   \
        if (__ballot(T >= T_THR) == 0ULL) break;  /* uniform decision */    \
    }

    {
        int pA[8], pB[8];
        float4 raA[8], rbA[8], raB[8], rbB[8];
        if (ngroups > 0) LOAD_GRP(pA, raA, rbA, wv * 8)
        for (int g = 0; g < ngroups; ++g) {
            if (g & 1) {
                PROC_GRP(raB, rbB, pA, raA, rbA, g)
            } else {
                PROC_GRP(raA, rbA, pB, raB, rbB, g)
            }
        }
    }

    s_rgb[wv][lane * 3 + 0] = accr;
    s_rgb[wv][lane * 3 + 1] = accg;
    s_rgb[wv][lane * 3 + 2] = accb;
    __syncthreads();

    // ---- Final reduce: 192 outputs (64 px x 3 ch) ----
    if (tid < 192) {
        float sum = 0.0f;
#pragma unroll
        for (int w = 0; w < 8; ++w) sum += s_rgb[w][tid];
        int p2 = tid / 3;
        int ch = tid - p2 * 3;
        int opx = tx * 8 + (p2 & 7);
        int opy = ty * 8 + (p2 >> 3);
        out[((size_t)opy * IMG_W + opx) * 3 + ch] = sum;
    }
}

extern "C" void kernel_launch(void* const* d_in, const int* in_sizes, int n_in,
                              void* d_out, int out_size, void* d_ws, size_t ws_size,
                              hipStream_t stream) {
    const float* means2d = (const float*)d_in[0];
    const float* conics  = (const float*)d_in[1];
    const float* colors  = (const float*)d_in[2];
    const float* opac    = (const float*)d_in[3];
    const float* depths  = (const float*)d_in[4];
    float* out = (float*)d_out;

    raster_fused<<<256, 512, 0, stream>>>(means2d, conics, colors, opac, depths, out);
}